// Round 10
// baseline (379.950 us; speedup 1.0000x reference)
//
#include <hip/hip_runtime.h>
#include <cmath>

#define HH 256
#define WW 256
#define RAD 12
#define KLEN 25
#define NMAPS 512
#define ESTRIP 16
#define NSTRIP (HH / ESTRIP)   // 16 strips per map
#define NMACRO 3               // 3 x 5-row macros + 3-row tail = 18 = ESTRIP+2
#define RING 29                // 24 carried + 5 fresh slots per macro-iter

typedef float v2f __attribute__((ext_vector_type(2)));

// ---------------------------------------------------------------------------
// Kernel A: 256-thread blocks = 4 INDEPENDENT strip-waves. Each wave: 64
// lanes x 4 cols. Vertical conv from a 29-slot v2f register ring (pk-FMA,
// static indices, 5-row macros, rotate-by-5). Horizontal conv via 7 aligned
// ds_read_b128 from a per-wave padded LDS row. No __syncthreads.
// launch_bounds(256,4): waves-per-EU target 4 (VGPR budget 128 >= 108).
// ---------------------------------------------------------------------------
__global__ __launch_bounds__(256, 4) void blur_peak_strip(
    const float* __restrict__ in,
    float* __restrict__ sval,
    int* __restrict__ sidx,
    int* __restrict__ scnt)
{
    __shared__ __align__(16) float vrow[4][WW + 2 * RAD];   // per-wave slice

    const int tid  = threadIdx.x;
    const int l    = tid & 63;           // lane, owns cols 4l..4l+3
    const int wv   = tid >> 6;
    const int sid  = blockIdx.x * 4 + wv;    // strip id 0..8191
    const int m     = sid >> 4;              // map
    const int strip = sid & 15;              // strip within map
    const float4* map4 = reinterpret_cast<const float4*>(in) + (size_t)m * (HH * WW / 4);

    const int e0 = strip * ESTRIP;
    const int o0 = e0 - 1;

    // Gaussian taps (identical float32 math to R2-R9; folds at compile time).
    float kf[KLEN];
    {
        float s = 0.f; float h[RAD + 1];
#pragma unroll
        for (int i = 0; i <= RAD; ++i) {
            float tt = (float)(i - RAD);
            h[i] = expf(-(tt * tt) / 18.0f);
            s += (i < RAD) ? 2.f * h[i] : h[i];
        }
#pragma unroll
        for (int i = 0; i <= RAD; ++i) h[i] /= s;
#pragma unroll
        for (int i = 0; i < KLEN; ++i) kf[i] = h[(i <= RAD) ? i : (2 * RAD - i)];
    }

    // Ring: slot i holds padded[oT + i], oT = o0 + 5*T; padded[q] = raw[mirr(q-12)]
    // Stored as pairs: rxy = cols {4l,4l+1}, rzw = cols {4l+2,4l+3}.
    v2f rxy[RING], rzw[RING];
#pragma unroll
    for (int i = 0; i < RING; ++i) {
        int q = o0 + i - RAD;
        int r = (q < 0) ? (-q - 1) : q;    // top mirror only (bottom impossible here)
        float4 t4 = map4[(size_t)r * (WW / 4) + l];
        rxy[i] = (v2f){t4.x, t4.y};
        rzw[i] = (v2f){t4.z, t4.w};
    }

    float4 g0v  = make_float4(0.f, 0.f, 0.f, 0.f);
    float4 gm1v = g0v, gm2v = g0v;
    float bval = -1.f;
    int   bidx = 0x7FFFFFFF;
    int   cnt  = 0;
    float* vr = vrow[wv];
    float4 pf0, pf1, pf2, pf3, pf4;

// issue next macro-iter's 5 row loads; consumed by ROTATE at macro end.
// raw row of first prefetch: (oT + 29) - 12 = o0 + 5T + 17  (never < 0)
#define PREFETCH(TT)                                                          \
    {                                                                         \
        int rb = o0 + 5 * (TT) + 17;                                          \
        int r0 = rb, r1 = rb + 1, r2 = rb + 2, r3 = rb + 3, r4 = rb + 4;      \
        if (r0 > HH - 1) r0 = 2 * HH - 1 - r0;                                \
        if (r1 > HH - 1) r1 = 2 * HH - 1 - r1;                                \
        if (r2 > HH - 1) r2 = 2 * HH - 1 - r2;                                \
        if (r3 > HH - 1) r3 = 2 * HH - 1 - r3;                                \
        if (r4 > HH - 1) r4 = 2 * HH - 1 - r4;                                \
        pf0 = map4[(size_t)r0 * (WW / 4) + l];                                \
        pf1 = map4[(size_t)r1 * (WW / 4) + l];                                \
        pf2 = map4[(size_t)r2 * (WW / 4) + l];                                \
        pf3 = map4[(size_t)r3 * (WW / 4) + l];                                \
        pf4 = map4[(size_t)r4 * (WW / 4) + l];                                \
    }

#define ROTATE()                                                              \
    {                                                                         \
        _Pragma("unroll")                                                     \
        for (int i = 0; i < RING - 5; ++i) {                                  \
            rxy[i] = rxy[i + 5]; rzw[i] = rzw[i + 5];                         \
        }                                                                     \
        rxy[24] = (v2f){pf0.x, pf0.y}; rzw[24] = (v2f){pf0.z, pf0.w};         \
        rxy[25] = (v2f){pf1.x, pf1.y}; rzw[25] = (v2f){pf1.z, pf1.w};         \
        rxy[26] = (v2f){pf2.x, pf2.y}; rzw[26] = (v2f){pf2.z, pf2.w};         \
        rxy[27] = (v2f){pf3.x, pf3.y}; rzw[27] = (v2f){pf3.z, pf3.w};         \
        rxy[28] = (v2f){pf4.x, pf4.y}; rzw[28] = (v2f){pf4.z, pf4.w};         \
    }

// one output row: g row o = oT + PP; all ring indices compile-time constants
#define ROW(TT, PP)                                                           \
    {                                                                         \
        v2f vxy = (v2f){0.f, 0.f};                                            \
        v2f vzw = (v2f){0.f, 0.f};                                            \
        _Pragma("unroll")                                                     \
        for (int d = 0; d < KLEN; ++d) {                                      \
            vxy += kf[d] * rxy[(PP) + d];                                     \
            vzw += kf[d] * rzw[(PP) + d];                                     \
        }                                                                     \
        reinterpret_cast<float4*>(vr + RAD)[l] =                              \
            make_float4(vxy.x, vxy.y, vzw.x, vzw.y);                          \
        if (l < 3)   reinterpret_cast<float4*>(vr)[2 - l]   =                 \
            make_float4(vzw.y, vzw.x, vxy.y, vxy.x);                          \
        if (l >= 61) reinterpret_cast<float4*>(vr)[130 - l] =                 \
            make_float4(vzw.y, vzw.x, vxy.y, vxy.x);                          \
        __builtin_amdgcn_wave_barrier();                                      \
        float acc0 = 0.f, acc1 = 0.f, acc2 = 0.f, acc3 = 0.f;                 \
        _Pragma("unroll")                                                     \
        for (int k = 0; k < 7; ++k) {                                         \
            float4 t4 = reinterpret_cast<const float4*>(vr)[l + k];           \
            _Pragma("unroll")                                                 \
            for (int e = 0; e < 4; ++e) {                                     \
                const int i = 4 * k + e;                                      \
                const float wval = (e==0)?t4.x:(e==1)?t4.y:(e==2)?t4.z:t4.w;  \
                if (i <= 24)           acc0 += kf[i]     * wval;              \
                if (i >= 1 && i <= 25) acc1 += kf[i - 1] * wval;              \
                if (i >= 2 && i <= 26) acc2 += kf[i - 2] * wval;              \
                if (i >= 3)            acc3 += kf[i - 3] * wval;              \
            }                                                                 \
        }                                                                     \
        __builtin_amdgcn_wave_barrier();                                      \
        gm2v = gm1v; gm1v = g0v;                                              \
        g0v = make_float4(acc0, acc1, acc2, acc3);                            \
        if ((TT) > 0 || (PP) >= 2) {                                          \
            const int erow = o0 + 5 * (TT) + (PP) - 1;                        \
            float lf0 = __shfl_up(gm1v.w, 1);   if (l == 0)  lf0 = 0.f;       \
            float rt3 = __shfl_down(gm1v.x, 1); if (l == 63) rt3 = 0.f;       \
            const bool etop = (erow == 0), ebot = (erow == HH - 1);           \
            const float gm1a[4] = {gm1v.x, gm1v.y, gm1v.z, gm1v.w};           \
            const float gm2a[4] = {gm2v.x, gm2v.y, gm2v.z, gm2v.w};           \
            const float g0a[4]  = {g0v.x,  g0v.y,  g0v.z,  g0v.w};            \
            const float mva[4]  = {rxy[(PP) + 11].x, rxy[(PP) + 11].y,        \
                                   rzw[(PP) + 11].x, rzw[(PP) + 11].y};       \
            _Pragma("unroll")                                                 \
            for (int q = 0; q < 4; ++q) {                                     \
                float gE = gm1a[q];                                           \
                float up = etop ? 0.f : gm2a[q];                              \
                float dn = ebot ? 0.f : g0a[q];                               \
                float lf = (q == 0) ? lf0 : gm1a[q - 1];                      \
                float rt = (q == 3) ? rt3 : gm1a[q + 1];                      \
                float mx = fmaxf(fmaxf(up, dn), fmaxf(lf, rt));               \
                bool pk = (gE >= mx) && (gE > 0.01f);                         \
                cnt += pk ? 1 : 0;                                            \
                float mv = mva[q];                                            \
                int fi = erow * WW + 4 * l + q;                               \
                bool upd = pk && (mv > bval);                                 \
                bval = upd ? mv : bval;                                       \
                bidx = upd ? fi : bidx;                                       \
            }                                                                 \
        }                                                                     \
    }

#pragma unroll 1
    for (int T = 0; T < NMACRO; ++T) {   // rows t = 5T .. 5T+4  (0..14)
        PREFETCH(T);
        ROW(T, 0); ROW(T, 1); ROW(T, 2); ROW(T, 3); ROW(T, 4);
        ROTATE();
    }
    // tail: rows t = 15..17 (static; ring slots 0..26 used, no prefetch)
    ROW(NMACRO, 0); ROW(NMACRO, 1); ROW(NMACRO, 2);

#undef ROW
#undef ROTATE
#undef PREFETCH

    // ---- 64-lane butterfly: (max val, min idx on tie), sum count ----
#pragma unroll
    for (int off = 32; off > 0; off >>= 1) {
        float v2 = __shfl_xor(bval, off);
        int   i2 = __shfl_xor(bidx, off);
        int   c2 = __shfl_xor(cnt,  off);
        if (v2 > bval || (v2 == bval && i2 < bidx)) { bval = v2; bidx = i2; }
        cnt += c2;
    }
    if (l == 0) { sval[sid] = bval; sidx[sid] = bidx; scnt[sid] = cnt; }
}

// ---------------------------------------------------------------------------
// Kernel B: per-map combine strips + 5x5 window sums at winner + output logic
// ---------------------------------------------------------------------------
__global__ __launch_bounds__(256) void finalize_kernel(
    const float* __restrict__ in,
    const float* __restrict__ sval,
    const int* __restrict__ sidx,
    const int* __restrict__ scnt,
    float* __restrict__ out)
{
    int t = blockIdx.x * blockDim.x + threadIdx.x;
    if (t >= NMAPS) return;

    float BV = -1.f; int BI = 0x7FFFFFFF; int C = 0;
#pragma unroll
    for (int s2 = 0; s2 < NSTRIP; ++s2) {
        int k = t * NSTRIP + s2;
        float v = sval[k]; int i = sidx[k];
        if (v > BV || (v == BV && i < BI)) { BV = v; BI = i; }
        C += scnt[k];
    }

    bool valid = (C == 1) || ((C > 1) && (BV >= 0.8f));

    float kx = -999.999f, ky = -999.999f, conf = 0.f;
    if (valid) {
        int pr = BI / WW, pc = BI % WW;
        const float* map = in + (size_t)t * HH * WW;
        float S = 0.f, SX = 0.f, SY = 0.f;
#pragma unroll
        for (int dr = -2; dr <= 2; ++dr) {
            int r = pr + dr;
            if (r < 0 || r >= HH) continue;
#pragma unroll
            for (int dc = -2; dc <= 2; ++dc) {
                int cc = pc + dc;
                if (cc < 0 || cc >= WW) continue;
                float mv = map[r * WW + cc];
                S  += mv;
                SX += mv * (float)cc;
                SY += mv * (float)r;
            }
        }
        float x = (S == 0.f) ? (float)pc : (SX / S);
        float y = (S == 0.f) ? (float)pr : (SY / S);
        kx = x + 0.4395f;
        ky = y + 0.4395f;
        conf = 1.f;
    }
    out[t * 3 + 0] = kx;
    out[t * 3 + 1] = ky;
    out[t * 3 + 2] = conf;
}

extern "C" void kernel_launch(void* const* d_in, const int* in_sizes, int n_in,
                              void* d_out, int out_size, void* d_ws, size_t ws_size,
                              hipStream_t stream) {
    const float* in = (const float*)d_in[0];
    float* out = (float*)d_out;

    const int nstrips = NMAPS * NSTRIP;   // 8192
    float* sval = (float*)d_ws;
    int*   sidx = (int*)((char*)d_ws + (size_t)nstrips * 4);
    int*   scnt = (int*)((char*)d_ws + (size_t)nstrips * 8);

    blur_peak_strip<<<nstrips / 4, 256, 0, stream>>>(in, sval, sidx, scnt);
    finalize_kernel<<<(NMAPS + 255) / 256, 256, 0, stream>>>(in, sval, sidx, scnt, out);
}

// Round 11
// 126.928 us; speedup vs baseline: 2.9934x; 2.9934x over previous
//
#include <hip/hip_runtime.h>
#include <cmath>

#define HH 256
#define WW 256
#define RAD 12
#define KLEN 25
#define NMAPS 512
#define ESTRIP 64
#define NSTRIP (HH / ESTRIP)   // 4 strips per map
#define RING 29                // 24 carried + 5 fresh slots per macro

typedef float v2f __attribute__((ext_vector_type(2)));

// ---------------------------------------------------------------------------
// Kernel A: NO LDS. 256-thread blocks = 4 independent strip-waves; 64 lanes
// x 4 cols. Conv order swapped (H then V): horizontal conv reads each lane's
// 28-col window straight from global (7 coalesced float4 loads, symmetric
// column padding via mirrored slots + register reversal); vertical conv from
// a 29-slot v2f register ring (static indices, rotate-by-5 macros, pk-FMA).
// Window loads prefetched one row ahead; raw argmax rows prefetched 5/macro.
// NOTE: no min-waves launch-bounds arg — R9/R10 showed it caps VGPR (128/64)
// and forces catastrophic scratch spill. Live set ~160 VGPR must stay in regs.
// ---------------------------------------------------------------------------
__global__ __launch_bounds__(256) void blur_peak_strip(
    const float* __restrict__ in,
    float* __restrict__ sval,
    int* __restrict__ sidx,
    int* __restrict__ scnt)
{
    const int tid = threadIdx.x;
    const int l   = tid & 63;               // lane, owns cols 4l..4l+3
    const int wv  = tid >> 6;
    const int sid = blockIdx.x * 4 + wv;    // strip id 0..2047
    const int m     = sid >> 2;             // map
    const int strip = sid & 3;              // strip within map
    const float4* map4 = reinterpret_cast<const float4*>(in) + (size_t)m * (HH * WW / 4);

    const int e0 = strip * ESTRIP;
    const int o0 = e0 - 1;

    // Gaussian taps (same float32 construction as R2-R10; folds at compile time)
    float kf[KLEN];
    {
        float s = 0.f; float h[RAD + 1];
#pragma unroll
        for (int i = 0; i <= RAD; ++i) {
            float tt = (float)(i - RAD);
            h[i] = expf(-(tt * tt) / 18.0f);
            s += (i < RAD) ? 2.f * h[i] : h[i];
        }
#pragma unroll
        for (int i = 0; i <= RAD; ++i) h[i] /= s;
#pragma unroll
        for (int i = 0; i < KLEN; ++i) kf[i] = h[(i <= RAD) ? i : (2 * RAD - i)];
    }

    // Window slots + reversal flags (row-independent). Lane window = padded
    // cols 4l-12..4l+15 = float4 slots l-3..l+3; mirrored at image edges.
    int  voffk[7];
    bool rv[7];
#pragma unroll
    for (int k = 0; k < 7; ++k) {
        int s_ = l - 3 + k;
        int v  = (s_ < 0) ? (-1 - s_) : ((s_ > 63) ? (127 - s_) : s_);
        voffk[k] = v;
        rv[k]    = (s_ < 0) || (s_ > 63);
    }

    // h ring: slot i holds h row (h-step) s' = i + 5T - 24 during macro T
    v2f hxy[RING], hzw[RING];
#pragma unroll
    for (int i = 0; i < RING; ++i) { hxy[i] = (v2f){0.f, 0.f}; hzw[i] = (v2f){0.f, 0.f}; }

    float4 W[7];        // current H window (row of h-step s)
    float4 pr[5];       // raw rows for this macro's evals (argmax values)
    float4 g0v = make_float4(0.f, 0.f, 0.f, 0.f), gm1v = g0v, gm2v = g0v;
    float bval = -1.f;
    int   bidx = 0x7FFFFFFF;
    int   cnt  = 0;

    // preload window for s=0: raw row o0-12 (top mirror possible)
    {
        int hr = o0 - 12;
        int r = (hr < 0) ? (-1 - hr) : hr;
        const float4* rp = map4 + (size_t)r * (WW / 4);
#pragma unroll
        for (int k = 0; k < 7; ++k) W[k] = rp[voffk[k]];
    }

// issue window loads for h-step SNEXT (consumed next row)
#define WLOAD(SNEXT)                                                          \
    {                                                                         \
        int hr_ = o0 - 12 + (SNEXT);                                          \
        int r_ = (hr_ < 0) ? (-1 - hr_) : ((hr_ > HH - 1) ? (2 * HH - 1 - hr_) : hr_); \
        const float4* rp_ = map4 + (size_t)r_ * (WW / 4);                     \
        _Pragma("unroll")                                                     \
        for (int k = 0; k < 7; ++k) W[k] = rp_[voffk[k]];                     \
    }

// horizontal conv of current window -> push h into ring slot 24+PP
#define HSTEP(PP)                                                             \
    {                                                                         \
        float w_[28];                                                         \
        _Pragma("unroll")                                                     \
        for (int k = 0; k < 7; ++k) {                                         \
            float a = W[k].x, b = W[k].y, c = W[k].z, d = W[k].w;             \
            if (k != 3) {                                                     \
                bool r_ = rv[k];                                              \
                float a2 = r_ ? d : a, b2 = r_ ? c : b;                       \
                float c2 = r_ ? b : c, d2 = r_ ? a : d;                       \
                a = a2; b = b2; c = c2; d = d2;                               \
            }                                                                 \
            w_[4*k] = a; w_[4*k+1] = b; w_[4*k+2] = c; w_[4*k+3] = d;         \
        }                                                                     \
        float a0 = 0.f, a1 = 0.f, a2 = 0.f, a3 = 0.f;                         \
        _Pragma("unroll")                                                     \
        for (int i = 0; i < 28; ++i) {                                        \
            if (i <= 24)           a0 += kf[i]     * w_[i];                   \
            if (i >= 1 && i <= 25) a1 += kf[i - 1] * w_[i];                   \
            if (i >= 2 && i <= 26) a2 += kf[i - 2] * w_[i];                   \
            if (i >= 3)            a3 += kf[i - 3] * w_[i];                   \
        }                                                                     \
        hxy[24 + (PP)] = (v2f){a0, a1};                                       \
        hzw[24 + (PP)] = (v2f){a2, a3};                                       \
    }

// vertical conv over ring slots PP..PP+24 -> g history shift
#define VSTEP(PP)                                                             \
    {                                                                         \
        v2f gx = (v2f){0.f, 0.f}, gz = (v2f){0.f, 0.f};                       \
        _Pragma("unroll")                                                     \
        for (int d = 0; d < KLEN; ++d) {                                      \
            gx += kf[d] * hxy[(PP) + d];                                      \
            gz += kf[d] * hzw[(PP) + d];                                      \
        }                                                                     \
        gm2v = gm1v; gm1v = g0v;                                              \
        g0v = make_float4(gx.x, gx.y, gz.x, gz.y);                            \
    }

// peak eval of row EROW (center = gm1v), argmax value from pr[PP]
#define ESTEP(PP, EROW, ETOP, EBOT)                                           \
    {                                                                         \
        const int erow_ = (EROW);                                             \
        float lf0 = __shfl_up(gm1v.w, 1);   if (l == 0)  lf0 = 0.f;           \
        float rt3 = __shfl_down(gm1v.x, 1); if (l == 63) rt3 = 0.f;           \
        const float gm1a[4] = {gm1v.x, gm1v.y, gm1v.z, gm1v.w};               \
        const float gm2a[4] = {gm2v.x, gm2v.y, gm2v.z, gm2v.w};               \
        const float g0a[4]  = {g0v.x,  g0v.y,  g0v.z,  g0v.w};                \
        const float mva[4]  = {pr[PP].x, pr[PP].y, pr[PP].z, pr[PP].w};       \
        _Pragma("unroll")                                                     \
        for (int q = 0; q < 4; ++q) {                                         \
            float gE = gm1a[q];                                               \
            float up = (ETOP) ? 0.f : gm2a[q];                                \
            float dn = (EBOT) ? 0.f : g0a[q];                                 \
            float lf = (q == 0) ? lf0 : gm1a[q - 1];                          \
            float rt = (q == 3) ? rt3 : gm1a[q + 1];                          \
            float mx = fmaxf(fmaxf(up, dn), fmaxf(lf, rt));                   \
            bool pk = (gE >= mx) && (gE > 0.01f);                             \
            cnt += pk ? 1 : 0;                                                \
            float mv = mva[q];                                                \
            int fi = (erow_ << 8) + 4 * l + q;                                \
            bool upd = pk && (mv > bval);                                     \
            bval = upd ? mv : bval;                                           \
            bidx = upd ? fi : bidx;                                           \
        }                                                                     \
    }

#define ROTATE()                                                              \
    {                                                                         \
        _Pragma("unroll")                                                     \
        for (int i = 0; i < RING - 5; ++i) { hxy[i] = hxy[i + 5]; hzw[i] = hzw[i + 5]; } \
    }

// raw rows for this macro's evals: rows o0 + 5*TBASE - 25 + p (clamped low)
#define RAWPF(TBASE)                                                          \
    {                                                                         \
        _Pragma("unroll")                                                     \
        for (int p_ = 0; p_ < 5; ++p_) {                                      \
            int rr_ = o0 + 5 * (TBASE) - 25 + p_;                             \
            rr_ = rr_ < 0 ? 0 : rr_;                                          \
            pr[p_] = map4[(size_t)rr_ * (WW / 4) + l];                        \
        }                                                                     \
    }

#define FULLROW(PP, SNEXT, EROW, ETOP, EBOT)                                  \
    HSTEP(PP); WLOAD(SNEXT); VSTEP(PP); ESTEP(PP, EROW, ETOP, EBOT);

    // ---- warmup: T = 0..3 (h-steps 0..19, H only) ----
#pragma unroll 1
    for (int T = 0; T < 4; ++T) {
        HSTEP(0); WLOAD(5 * T + 1);
        HSTEP(1); WLOAD(5 * T + 2);
        HSTEP(2); WLOAD(5 * T + 3);
        HSTEP(3); WLOAD(5 * T + 4);
        HSTEP(4); WLOAD(5 * T + 5);
        ROTATE();
    }
    // ---- T = 4 (s=20..24): first V at s=24 ----
    {
        HSTEP(0); WLOAD(21);
        HSTEP(1); WLOAD(22);
        HSTEP(2); WLOAD(23);
        HSTEP(3); WLOAD(24);
        HSTEP(4); WLOAD(25); VSTEP(4);
        ROTATE();
    }
    // ---- T = 5 (s=25..29): first eval at s=26 (row e0; top edge if strip 0) --
    {
        RAWPF(5);
        HSTEP(0); WLOAD(26); VSTEP(0);
        FULLROW(1, 27, o0 + 1, (strip == 0), false);
        FULLROW(2, 28, o0 + 2, false, false);
        FULLROW(3, 29, o0 + 3, false, false);
        FULLROW(4, 30, o0 + 4, false, false);
        ROTATE();
    }
    // ---- main loop: T = 6..16, fully active, no guards ----
#pragma unroll 1
    for (int T = 6; T < 17; ++T) {
        RAWPF(T);
        FULLROW(0, 5 * T + 1, o0 + 5 * T - 25, false, false);
        FULLROW(1, 5 * T + 2, o0 + 5 * T - 24, false, false);
        FULLROW(2, 5 * T + 3, o0 + 5 * T - 23, false, false);
        FULLROW(3, 5 * T + 4, o0 + 5 * T - 22, false, false);
        FULLROW(4, 5 * T + 5, o0 + 5 * T - 21, false, false);
        ROTATE();
    }
    // ---- T = 17 (s=85..89): last rows; bottom edge if strip 3 ----
    {
        RAWPF(17);
        FULLROW(0, 86, o0 + 60, false, false);
        FULLROW(1, 87, o0 + 61, false, false);
        FULLROW(2, 88, o0 + 62, false, false);
        FULLROW(3, 89, o0 + 63, false, false);
        HSTEP(4); VSTEP(4); ESTEP(4, o0 + 64, false, (strip == 3));
    }

#undef FULLROW
#undef RAWPF
#undef ROTATE
#undef ESTEP
#undef VSTEP
#undef HSTEP
#undef WLOAD

    // ---- 64-lane butterfly: (max val, min idx on tie), sum count ----
#pragma unroll
    for (int off = 32; off > 0; off >>= 1) {
        float v2 = __shfl_xor(bval, off);
        int   i2 = __shfl_xor(bidx, off);
        int   c2 = __shfl_xor(cnt,  off);
        if (v2 > bval || (v2 == bval && i2 < bidx)) { bval = v2; bidx = i2; }
        cnt += c2;
    }
    if (l == 0) { sval[sid] = bval; sidx[sid] = bidx; scnt[sid] = cnt; }
}

// ---------------------------------------------------------------------------
// Kernel B: per-map combine strips + 5x5 window sums at winner + output logic
// ---------------------------------------------------------------------------
__global__ __launch_bounds__(256) void finalize_kernel(
    const float* __restrict__ in,
    const float* __restrict__ sval,
    const int* __restrict__ sidx,
    const int* __restrict__ scnt,
    float* __restrict__ out)
{
    int t = blockIdx.x * blockDim.x + threadIdx.x;
    if (t >= NMAPS) return;

    float BV = -1.f; int BI = 0x7FFFFFFF; int C = 0;
#pragma unroll
    for (int s2 = 0; s2 < NSTRIP; ++s2) {
        int k = t * NSTRIP + s2;
        float v = sval[k]; int i = sidx[k];
        if (v > BV || (v == BV && i < BI)) { BV = v; BI = i; }
        C += scnt[k];
    }

    bool valid = (C == 1) || ((C > 1) && (BV >= 0.8f));

    float kx = -999.999f, ky = -999.999f, conf = 0.f;
    if (valid) {
        int pr = BI / WW, pc = BI % WW;
        const float* map = in + (size_t)t * HH * WW;
        float S = 0.f, SX = 0.f, SY = 0.f;
#pragma unroll
        for (int dr = -2; dr <= 2; ++dr) {
            int r = pr + dr;
            if (r < 0 || r >= HH) continue;
#pragma unroll
            for (int dc = -2; dc <= 2; ++dc) {
                int cc = pc + dc;
                if (cc < 0 || cc >= WW) continue;
                float mv = map[r * WW + cc];
                S  += mv;
                SX += mv * (float)cc;
                SY += mv * (float)r;
            }
        }
        float x = (S == 0.f) ? (float)pc : (SX / S);
        float y = (S == 0.f) ? (float)pr : (SY / S);
        kx = x + 0.4395f;
        ky = y + 0.4395f;
        conf = 1.f;
    }
    out[t * 3 + 0] = kx;
    out[t * 3 + 1] = ky;
    out[t * 3 + 2] = conf;
}

extern "C" void kernel_launch(void* const* d_in, const int* in_sizes, int n_in,
                              void* d_out, int out_size, void* d_ws, size_t ws_size,
                              hipStream_t stream) {
    const float* in = (const float*)d_in[0];
    float* out = (float*)d_out;

    const int nstrips = NMAPS * NSTRIP;   // 2048
    float* sval = (float*)d_ws;
    int*   sidx = (int*)((char*)d_ws + (size_t)nstrips * 4);
    int*   scnt = (int*)((char*)d_ws + (size_t)nstrips * 8);

    blur_peak_strip<<<nstrips / 4, 256, 0, stream>>>(in, sval, sidx, scnt);
    finalize_kernel<<<(NMAPS + 255) / 256, 256, 0, stream>>>(in, sval, sidx, scnt, out);
}

// Round 12
// 81.412 us; speedup vs baseline: 4.6670x; 1.5591x over previous
//
#include <hip/hip_runtime.h>
#include <cmath>

#define HH 256
#define WW 256
#define RAD 12
#define KLEN 25
#define NMAPS 512
#define ESTRIP 32
#define NSTRIP (HH / ESTRIP)   // 8 strips per map
#define RING 29                // 24 carried + 5 fresh slots per macro-iter

typedef float v2f __attribute__((ext_vector_type(2)));

// ---------------------------------------------------------------------------
// Kernel A: 256-thread blocks = 4 INDEPENDENT strip-waves; 64 lanes x 4 cols.
// Software-pipelined row schedule (1-row skew, fully static):
//   iter t: read v(t-1) window from LDS buf[(t-1)&1]  (written ~250 instr ago)
//           VC(t) from 29-slot v2f register ring       (covers read latency)
//           write v(t) to buf[t&1]
//           HC(t-1) from read registers
//           eval row t-2
// All ring/buffer indices compile-time; warmup (t=0..2) and tail (t=34)
// statically peeled — no runtime stage guards (R7's spill cause).
// No min-waves launch-bounds arg (R9/R10: it caps VGPR and forces spill).
// ---------------------------------------------------------------------------
__global__ __launch_bounds__(256) void blur_peak_strip(
    const float* __restrict__ in,
    float* __restrict__ sval,
    int* __restrict__ sidx,
    int* __restrict__ scnt)
{
    __shared__ __align__(16) float vrow[4][2][WW + 2 * RAD];  // per-wave dbuf

    const int tid  = threadIdx.x;
    const int l    = tid & 63;           // lane, owns cols 4l..4l+3
    const int wv   = tid >> 6;
    const int sid  = blockIdx.x * 4 + wv;    // strip id 0..4095
    const int m     = sid >> 3;              // map
    const int strip = sid & 7;               // strip within map
    const float4* map4 = reinterpret_cast<const float4*>(in) + (size_t)m * (HH * WW / 4);

    const int e0 = strip * ESTRIP;
    const int o0 = e0 - 1;

    // Gaussian taps (identical float32 math to R2-R11; folds at compile time).
    float kf[KLEN];
    {
        float s = 0.f; float h[RAD + 1];
#pragma unroll
        for (int i = 0; i <= RAD; ++i) {
            float tt = (float)(i - RAD);
            h[i] = expf(-(tt * tt) / 18.0f);
            s += (i < RAD) ? 2.f * h[i] : h[i];
        }
#pragma unroll
        for (int i = 0; i <= RAD; ++i) h[i] /= s;
#pragma unroll
        for (int i = 0; i < KLEN; ++i) kf[i] = h[(i <= RAD) ? i : (2 * RAD - i)];
    }

    // Ring: slot i holds padded[oT + i], oT = o0 + 5*T; padded[q] = raw[mirr(q-12)]
    v2f rxy[RING], rzw[RING];
#pragma unroll
    for (int i = 0; i < RING; ++i) {
        int q = o0 + i - RAD;
        int r = (q < 0) ? (-q - 1) : q;    // top mirror only
        float4 t4 = map4[(size_t)r * (WW / 4) + l];
        rxy[i] = (v2f){t4.x, t4.y};
        rzw[i] = (v2f){t4.z, t4.w};
    }

    float4 g0v  = make_float4(0.f, 0.f, 0.f, 0.f);
    float4 gm1v = g0v, gm2v = g0v;
    float bval = -1.f;
    int   bidx = 0x7FFFFFFF;
    int   cnt  = 0;
    float4 pf0, pf1, pf2, pf3, pf4;

#define PREFETCH(TT)                                                          \
    {                                                                         \
        int rb = o0 + 5 * (TT) + 17;                                          \
        int r0 = rb, r1 = rb + 1, r2 = rb + 2, r3 = rb + 3, r4 = rb + 4;      \
        if (r0 > HH - 1) r0 = 2 * HH - 1 - r0;                                \
        if (r1 > HH - 1) r1 = 2 * HH - 1 - r1;                                \
        if (r2 > HH - 1) r2 = 2 * HH - 1 - r2;                                \
        if (r3 > HH - 1) r3 = 2 * HH - 1 - r3;                                \
        if (r4 > HH - 1) r4 = 2 * HH - 1 - r4;                                \
        pf0 = map4[(size_t)r0 * (WW / 4) + l];                                \
        pf1 = map4[(size_t)r1 * (WW / 4) + l];                                \
        pf2 = map4[(size_t)r2 * (WW / 4) + l];                                \
        pf3 = map4[(size_t)r3 * (WW / 4) + l];                                \
        pf4 = map4[(size_t)r4 * (WW / 4) + l];                                \
    }

#define ROTATE()                                                              \
    {                                                                         \
        _Pragma("unroll")                                                     \
        for (int i = 0; i < RING - 5; ++i) {                                  \
            rxy[i] = rxy[i + 5]; rzw[i] = rzw[i + 5];                         \
        }                                                                     \
        rxy[24] = (v2f){pf0.x, pf0.y}; rzw[24] = (v2f){pf0.z, pf0.w};         \
        rxy[25] = (v2f){pf1.x, pf1.y}; rzw[25] = (v2f){pf1.z, pf1.w};         \
        rxy[26] = (v2f){pf2.x, pf2.y}; rzw[26] = (v2f){pf2.z, pf2.w};         \
        rxy[27] = (v2f){pf3.x, pf3.y}; rzw[27] = (v2f){pf3.z, pf3.w};         \
        rxy[28] = (v2f){pf4.x, pf4.y}; rzw[28] = (v2f){pf4.z, pf4.w};         \
    }

// VC(t) from ring slots PP..PP+24 and write v(t) into buf[(TP)&1]
#define VCW(PP, TP)                                                           \
    {                                                                         \
        v2f vxy = (v2f){0.f, 0.f};                                            \
        v2f vzw = (v2f){0.f, 0.f};                                            \
        _Pragma("unroll")                                                     \
        for (int d = 0; d < KLEN; ++d) {                                      \
            vxy += kf[d] * rxy[(PP) + d];                                     \
            vzw += kf[d] * rzw[(PP) + d];                                     \
        }                                                                     \
        float* wb = vrow[wv][(TP) & 1];                                       \
        reinterpret_cast<float4*>(wb + RAD)[l] =                              \
            make_float4(vxy.x, vxy.y, vzw.x, vzw.y);                          \
        if (l < 3)   reinterpret_cast<float4*>(wb)[2 - l]   =                 \
            make_float4(vzw.y, vzw.x, vxy.y, vxy.x);                          \
        if (l >= 61) reinterpret_cast<float4*>(wb)[130 - l] =                 \
            make_float4(vzw.y, vzw.x, vxy.y, vxy.x);                          \
    }

// HC of row held in rd0..rd6 -> shift g history
#define HC()                                                                  \
    {                                                                         \
        float acc0 = 0.f, acc1 = 0.f, acc2 = 0.f, acc3 = 0.f;                 \
        const float4 rda[7] = {rd0, rd1, rd2, rd3, rd4, rd5, rd6};            \
        _Pragma("unroll")                                                     \
        for (int k = 0; k < 7; ++k) {                                         \
            _Pragma("unroll")                                                 \
            for (int e = 0; e < 4; ++e) {                                     \
                const int i = 4 * k + e;                                      \
                const float wval = (e == 0) ? rda[k].x : (e == 1) ? rda[k].y  \
                                 : (e == 2) ? rda[k].z : rda[k].w;            \
                if (i <= 24)           acc0 += kf[i]     * wval;              \
                if (i >= 1 && i <= 25) acc1 += kf[i - 1] * wval;              \
                if (i >= 2 && i <= 26) acc2 += kf[i - 2] * wval;              \
                if (i >= 3)            acc3 += kf[i - 3] * wval;              \
            }                                                                 \
        }                                                                     \
        gm2v = gm1v; gm1v = g0v;                                              \
        g0v = make_float4(acc0, acc1, acc2, acc3);                            \
    }

// eval row EROW (center gm1v), raw values from ring slot SLOT
#define EV(SLOT, EROW)                                                        \
    {                                                                         \
        const int erow = (EROW);                                              \
        float lf0 = __shfl_up(gm1v.w, 1);   if (l == 0)  lf0 = 0.f;           \
        float rt3 = __shfl_down(gm1v.x, 1); if (l == 63) rt3 = 0.f;           \
        const bool etop = (erow == 0), ebot = (erow == HH - 1);               \
        const float gm1a[4] = {gm1v.x, gm1v.y, gm1v.z, gm1v.w};               \
        const float gm2a[4] = {gm2v.x, gm2v.y, gm2v.z, gm2v.w};               \
        const float g0a[4]  = {g0v.x,  g0v.y,  g0v.z,  g0v.w};                \
        const float mva[4]  = {rxy[SLOT].x, rxy[SLOT].y,                      \
                               rzw[SLOT].x, rzw[SLOT].y};                     \
        _Pragma("unroll")                                                     \
        for (int q = 0; q < 4; ++q) {                                         \
            float gE = gm1a[q];                                               \
            float up = etop ? 0.f : gm2a[q];                                  \
            float dn = ebot ? 0.f : g0a[q];                                   \
            float lf = (q == 0) ? lf0 : gm1a[q - 1];                          \
            float rt = (q == 3) ? rt3 : gm1a[q + 1];                          \
            float mx = fmaxf(fmaxf(up, dn), fmaxf(lf, rt));                   \
            bool pk = (gE >= mx) && (gE > 0.01f);                             \
            cnt += pk ? 1 : 0;                                                \
            float mv = mva[q];                                                \
            int fi = erow * WW + 4 * l + q;                                   \
            bool upd = pk && (mv > bval);                                     \
            bval = upd ? mv : bval;                                           \
            bidx = upd ? fi : bidx;                                           \
        }                                                                     \
    }

// full pipelined row: t = 5*TB+PP (TB may be runtime; parity/slots static-ok)
// RD(t-1) -> VC(t)+write -> HC(t-1) -> EV(t-2)
#define ROW_FULL(TB, PP)                                                      \
    {                                                                         \
        const int tpar = ((TB) + (PP)) & 1;   /* parity of t since 5T+PP */   \
        const float4* rb4 =                                                   \
            reinterpret_cast<const float4*>(vrow[wv][tpar ^ 1]);              \
        float4 rd0 = rb4[l + 0], rd1 = rb4[l + 1], rd2 = rb4[l + 2],          \
               rd3 = rb4[l + 3], rd4 = rb4[l + 4], rd5 = rb4[l + 5],          \
               rd6 = rb4[l + 6];                                              \
        VCW(PP, tpar);                                                        \
        __builtin_amdgcn_wave_barrier();                                      \
        HC();                                                                 \
        EV((PP) + 10, o0 + 5 * (TB) + (PP) - 2);                              \
    }

// warmup row without eval (t = PP, TB=0)
#define ROW_NOEV(PP)                                                          \
    {                                                                         \
        const int tpar = (PP) & 1;                                            \
        const float4* rb4 =                                                   \
            reinterpret_cast<const float4*>(vrow[wv][tpar ^ 1]);              \
        float4 rd0 = rb4[l + 0], rd1 = rb4[l + 1], rd2 = rb4[l + 2],          \
               rd3 = rb4[l + 3], rd4 = rb4[l + 4], rd5 = rb4[l + 5],          \
               rd6 = rb4[l + 6];                                              \
        VCW(PP, PP);                                                          \
        __builtin_amdgcn_wave_barrier();                                      \
        HC();                                                                 \
    }

    // ---- T = 0: t=0 (VC only), t=1,2 (no eval), t=3,4 (full) ----
    PREFETCH(0);
    VCW(0, 0);
    __builtin_amdgcn_wave_barrier();
    ROW_NOEV(1);
    ROW_NOEV(2);
    ROW_FULL(0, 3);
    ROW_FULL(0, 4);
    ROTATE();

    // ---- main: T = 1..5, rows t = 5T..5T+4, all full ----
#pragma unroll 1
    for (int T = 1; T < 6; ++T) {
        PREFETCH(T);
        ROW_FULL(T, 0);
        ROW_FULL(T, 1);
        ROW_FULL(T, 2);
        ROW_FULL(T, 3);
        ROW_FULL(T, 4);
        ROTATE();
    }

    // ---- T = 6: t=30..33 full; t=34 tail (RD+HC+EV only) ----
    ROW_FULL(6, 0);
    ROW_FULL(6, 1);
    ROW_FULL(6, 2);
    ROW_FULL(6, 3);
    {
        // t = 34: read v(33) from buf[33&1]=buf[1], HC(33), EV(32)
        const float4* rb4 = reinterpret_cast<const float4*>(vrow[wv][1]);
        float4 rd0 = rb4[l + 0], rd1 = rb4[l + 1], rd2 = rb4[l + 2],
               rd3 = rb4[l + 3], rd4 = rb4[l + 4], rd5 = rb4[l + 5],
               rd6 = rb4[l + 6];
        HC();
        EV(14, o0 + 32);
    }

#undef ROW_NOEV
#undef ROW_FULL
#undef EV
#undef HC
#undef VCW
#undef ROTATE
#undef PREFETCH

    // ---- 64-lane butterfly: (max val, min idx on tie), sum count ----
#pragma unroll
    for (int off = 32; off > 0; off >>= 1) {
        float v2 = __shfl_xor(bval, off);
        int   i2 = __shfl_xor(bidx, off);
        int   c2 = __shfl_xor(cnt,  off);
        if (v2 > bval || (v2 == bval && i2 < bidx)) { bval = v2; bidx = i2; }
        cnt += c2;
    }
    if (l == 0) { sval[sid] = bval; sidx[sid] = bidx; scnt[sid] = cnt; }
}

// ---------------------------------------------------------------------------
// Kernel B: per-map combine strips + 5x5 window sums at winner + output logic
// ---------------------------------------------------------------------------
__global__ __launch_bounds__(256) void finalize_kernel(
    const float* __restrict__ in,
    const float* __restrict__ sval,
    const int* __restrict__ sidx,
    const int* __restrict__ scnt,
    float* __restrict__ out)
{
    int t = blockIdx.x * blockDim.x + threadIdx.x;
    if (t >= NMAPS) return;

    float BV = -1.f; int BI = 0x7FFFFFFF; int C = 0;
#pragma unroll
    for (int s2 = 0; s2 < NSTRIP; ++s2) {
        int k = t * NSTRIP + s2;
        float v = sval[k]; int i = sidx[k];
        if (v > BV || (v == BV && i < BI)) { BV = v; BI = i; }
        C += scnt[k];
    }

    bool valid = (C == 1) || ((C > 1) && (BV >= 0.8f));

    float kx = -999.999f, ky = -999.999f, conf = 0.f;
    if (valid) {
        int pr = BI / WW, pc = BI % WW;
        const float* map = in + (size_t)t * HH * WW;
        float S = 0.f, SX = 0.f, SY = 0.f;
#pragma unroll
        for (int dr = -2; dr <= 2; ++dr) {
            int r = pr + dr;
            if (r < 0 || r >= HH) continue;
#pragma unroll
            for (int dc = -2; dc <= 2; ++dc) {
                int cc = pc + dc;
                if (cc < 0 || cc >= WW) continue;
                float mv = map[r * WW + cc];
                S  += mv;
                SX += mv * (float)cc;
                SY += mv * (float)r;
            }
        }
        float x = (S == 0.f) ? (float)pc : (SX / S);
        float y = (S == 0.f) ? (float)pr : (SY / S);
        kx = x + 0.4395f;
        ky = y + 0.4395f;
        conf = 1.f;
    }
    out[t * 3 + 0] = kx;
    out[t * 3 + 1] = ky;
    out[t * 3 + 2] = conf;
}

extern "C" void kernel_launch(void* const* d_in, const int* in_sizes, int n_in,
                              void* d_out, int out_size, void* d_ws, size_t ws_size,
                              hipStream_t stream) {
    const float* in = (const float*)d_in[0];
    float* out = (float*)d_out;

    const int nstrips = NMAPS * NSTRIP;   // 4096
    float* sval = (float*)d_ws;
    int*   sidx = (int*)((char*)d_ws + (size_t)nstrips * 4);
    int*   scnt = (int*)((char*)d_ws + (size_t)nstrips * 8);

    blur_peak_strip<<<nstrips / 4, 256, 0, stream>>>(in, sval, sidx, scnt);
    finalize_kernel<<<(NMAPS + 255) / 256, 256, 0, stream>>>(in, sval, sidx, scnt, out);
}